// Round 7
// baseline (1029.410 us; speedup 1.0000x reference)
//
#include <hip/hip_runtime.h>
#include <stdint.h>

// ---------------------------------------------------------------------------
// DialogueTransformer: B=8,S=2048,D=1024,H=8,HD=128 -> 16384 tokens, fp32 I/O.
// Round 11: phase-PIPELINED frag reads (the m201 mechanism finally applied).
// Mechanism: MFMA issue is throughput-bound (a wave issuing a 16-MFMA cluster
// is pinned ~310cy/SIMD), so reads issued after a cluster can't overlap it.
// Fix: each phase issues the ds_reads for the NEXT phase's MFMA, then
// barriers, then MFMAs this phase (operands read LAST phase). The LDS pipe
// executes phase-k reads while the matrix pipe drains cluster k.
// Per K-tile t (buf dd=t&1, 4 phases, quadrants Q0..Q3 ordered so each phase
// needs ONE new operand):
//   p0: stage tile t+1 -> dd^1 (8 GLD16); read b1<-B1(t);   BAR; MFMA Q0(atop,b0)
//   p1: read abot<-Abot(t);                                 BAR; MFMA Q1(atop,b1)
//   p2: vmcnt(0) (publish tile t+1; LDS-idle window for DMA) BAR; MFMA Q2(abot,b1)
//   p3: read atop<-Atop(t+1), b0'<-B0(t+1) [from dd^1]      BAR; MFMA Q3(abot,b0)
// b0 is ping-ponged (read and last use share p3); atop/abot/b1 single-buffered.
// WAR: p0's stages overwrite tile t-1, last read at p1(t-1), 3 barriers prior.
// vmcnt(0) at p2: only tile t+1's 8 stages outstanding; distance ~2 phases
// (~1240cy) covers HBM latency. LDS 128KB: A dbuf 2x32KB + B dbuf 2x32KB.
// Attention + conversion kernels unchanged.
// ws layout: bA(32MB) | bB(32MB) | oseq(32MB) | wts(28MB) = 124MB.
// d_out (64MB) doubles as two 32MB bf16 scratch halves until the final GEMM.
// ---------------------------------------------------------------------------

#define TOKENS 16384
#define DMODEL 1024

typedef unsigned short ushort_t;
typedef __attribute__((ext_vector_type(8))) short short8;
typedef __attribute__((ext_vector_type(4))) float floatx4;

__device__ __forceinline__ float b2f(ushort_t u) {
  union { uint32_t i; float f; } v; v.i = ((uint32_t)u) << 16; return v.f;
}
__device__ __forceinline__ ushort_t f2b(float f) {
  union { float f; uint32_t i; } v; v.f = f;
  uint32_t r = v.i + 0x7fffu + ((v.i >> 16) & 1u);
  return (ushort_t)(r >> 16);
}

// load 8 fp32 (16B-aligned), round to bf16, store 16B
__device__ __forceinline__ void pack8(const float* __restrict__ g, ushort_t* dst) {
  float4 x = *(const float4*)g;
  float4 y = *(const float4*)(g + 4);
  ushort_t o[8] = {f2b(x.x), f2b(x.y), f2b(x.z), f2b(x.w),
                   f2b(y.x), f2b(y.y), f2b(y.z), f2b(y.w)};
  *(uint4*)dst = *(uint4*)o;
}

// async global->LDS, 16B per lane (wave-uniform base + lane*16)
#define GLD16(g, l)                                                          \
  __builtin_amdgcn_global_load_lds(                                          \
      (const __attribute__((address_space(1))) void*)(g),                    \
      (__attribute__((address_space(3))) void*)(l), 16, 0, 0)

// ---------------------------------------------------------------------------
// weight pre-conversion: 14 matrices of 1024x1024 fp32 -> bf16
// ---------------------------------------------------------------------------
struct ConvArgs {
  const float* src[14];
  ushort_t* dst[14];
};

__global__ __launch_bounds__(256) void conv_w_kernel(ConvArgs a) {
  const int w = blockIdx.y;
  const int idx = (blockIdx.x * 256 + threadIdx.x) * 8;
  pack8(a.src[w] + idx, a.dst[w] + idx);
}

// generic fp32 -> bf16 conversion (output_seq)
__global__ __launch_bounds__(256) void conv_x_kernel(
    const float* __restrict__ src, ushort_t* __restrict__ dst) {
  const int idx = (blockIdx.x * 256 + threadIdx.x) * 8;
  pack8(src + idx, dst + idx);
}

// x = input + pe (fp32 in, bf16 out)
__global__ __launch_bounds__(256) void add_pe_kernel(
    const float* __restrict__ in, const float* __restrict__ pe,
    ushort_t* __restrict__ out) {
  int idx = (blockIdx.x * 256 + threadIdx.x) * 8;
  int d = idx & (DMODEL - 1);
  float4 a0 = *(const float4*)(in + idx);
  float4 a1 = *(const float4*)(in + idx + 4);
  float4 p0 = *(const float4*)(pe + d);
  float4 p1 = *(const float4*)(pe + d + 4);
  ushort_t o[8] = {f2b(a0.x + p0.x), f2b(a0.y + p0.y), f2b(a0.z + p0.z), f2b(a0.w + p0.w),
                   f2b(a1.x + p1.x), f2b(a1.y + p1.y), f2b(a1.z + p1.z), f2b(a1.w + p1.w)};
  *(uint4*)(out + idx) = *(uint4*)o;
}

// ---------------------------------------------------------------------------
// GEMM helpers. LDS: sA + d*16384 (A tile [256][64] bf16, d=0..1),
// sB + d*16384 (B tile [256][64]). Rows 0-63 at [0,4096) etc. (8KB chunks of
// 64 rows). LDS slot (row, chunk j) holds global chunk j^(row&7) -- the
// proven conflict-free swizzle (pre-swizzled GLOBAL source; LDS dest linear,
// as global_load_lds requires). Frag read chunk = (kk*4+lq)^(row&7).
// ---------------------------------------------------------------------------
__device__ __forceinline__ void load_af(const ushort_t* p, int aoff, int cs0,
                                        int cs1, short8 (&af)[4][2]) {
  p += aoff;
#pragma unroll
  for (int i = 0; i < 4; i++) {
    af[i][0] = *(const short8*)&p[i * 1024 + cs0];
    af[i][1] = *(const short8*)&p[i * 1024 + cs1];
  }
}

__device__ __forceinline__ void load_bf(const ushort_t* p, int boff, int cs0,
                                        int cs1, short8 (&bf)[2][2]) {
  p += boff;
#pragma unroll
  for (int j = 0; j < 2; j++) {
    bf[j][0] = *(const short8*)&p[j * 1024 + cs0];
    bf[j][1] = *(const short8*)&p[j * 1024 + cs1];
  }
}

// one C-quadrant x K=64: 16 MFMA, setprio-wrapped (T5)
__device__ __forceinline__ void mfma_q(floatx4 (&accq)[4][2],
                                       const short8 (&af)[4][2],
                                       const short8 (&bf)[2][2]) {
  __builtin_amdgcn_s_setprio(1);
#pragma unroll
  for (int i = 0; i < 4; i++)
#pragma unroll
    for (int j = 0; j < 2; j++) {
      accq[i][j] = __builtin_amdgcn_mfma_f32_16x16x32_bf16(
          af[i][0], bf[j][0], accq[i][j], 0, 0, 0);
      accq[i][j] = __builtin_amdgcn_mfma_f32_16x16x32_bf16(
          af[i][1], bf[j][1], accq[i][j], 0, 0, 0);
    }
  __builtin_amdgcn_s_setprio(0);
}

// raw barrier: compiler memory-ordering point (pins ds/stage ops into their
// phase), no vmcnt drain, no sched_barrier (m141)
#define BARSB asm volatile("s_barrier" ::: "memory")

// stage a full 256x64 tile (32KB) of K-tile tk: 4 GLD16/thread.
// sources: rows rl+{0,64,128,192}; dests: 8KB chunks (64 rows each).
#define STAGE_A4(dst, tk)                                                    \
  do {                                                                       \
    GLD16(gA + (size_t)(tk) * 64, (dst) + lo);                               \
    GLD16(gA + (size_t)(tk) * 64 + 65536, (dst) + 4096 + lo);                \
    GLD16(gA + (size_t)(tk) * 64 + 131072, (dst) + 8192 + lo);               \
    GLD16(gA + (size_t)(tk) * 64 + 196608, (dst) + 12288 + lo);              \
  } while (0)
#define STAGE_B4(dst, tk)                                                    \
  do {                                                                       \
    GLD16(gB + (size_t)(tk) * 64, (dst) + lo);                               \
    GLD16(gB + (size_t)(tk) * 64 + 65536, (dst) + 4096 + lo);                \
    GLD16(gB + (size_t)(tk) * 64 + 131072, (dst) + 8192 + lo);               \
    GLD16(gB + (size_t)(tk) * 64 + 196608, (dst) + 12288 + lo);              \
  } while (0)

// one K-tile = 4 pipelined phases; see file header for the ledger.
// b0c = B0 regs for THIS tile; b0n = B0 regs being filled for tile tt+1.
#define GROUP(tt, dd, b0c, b0n)                                              \
  do {                                                                       \
    /* p0 */                                                                 \
    if ((tt) + 1 < NT) {                                                     \
      STAGE_A4(sA + ((dd) ^ 1) * 16384, (tt) + 1);                           \
      STAGE_B4(sB + ((dd) ^ 1) * 16384, (tt) + 1);                           \
    }                                                                        \
    load_bf(sB + (dd) * 16384 + 8192, boff, cs0, cs1, b1);                   \
    BARSB;                                                                   \
    mfma_q(acc[0], atop, b0c);                                               \
    /* p1 */                                                                 \
    load_af(sA + (dd) * 16384 + 8192, aoff, cs0, cs1, abot);                 \
    BARSB;                                                                   \
    mfma_q(acc[1], atop, b1);                                                \
    /* p2 */                                                                 \
    asm volatile("s_waitcnt vmcnt(0)" ::: "memory");                         \
    BARSB;                                                                   \
    mfma_q(acc[3], abot, b1);                                                \
    /* p3 */                                                                 \
    if ((tt) + 1 < NT) {                                                     \
      load_af(sA + ((dd) ^ 1) * 16384, aoff, cs0, cs1, atop);                \
      load_bf(sB + ((dd) ^ 1) * 16384, boff, cs0, cs1, b0n);                 \
    }                                                                        \
    BARSB;                                                                   \
    mfma_q(acc[2], abot, b0c);                                               \
  } while (0)

// ---------------------------------------------------------------------------
// C[t,n] = sum_k A[t,k]*W[n,k] + bias[n].  M=16384, N=K=1024. All-bf16 A/W.
// 256x256 tile, 8 waves; per C-quadrant (128x128) waves split 2x4 (64x32).
// ---------------------------------------------------------------------------
template <bool RELU, bool OUT32>
__global__ __launch_bounds__(512, 2) void gemm_bt(
    const ushort_t* __restrict__ A, const ushort_t* __restrict__ W,
    const float* __restrict__ bias, void* __restrict__ Cp) {
  constexpr int K = 1024, N = 1024, NT = 16;  // NT = K / BK, BK = 64
  extern __shared__ ushort_t smem[];
  ushort_t* sA = smem;           // 2 x 16384 elems (2 x 32 KiB)
  ushort_t* sB = smem + 32768;   // 2 x 16384 elems

  const int tid = threadIdx.x;
  const int lane = tid & 63;
  const int wid = tid >> 6;

  // XCD-bijective swizzle: 256 wgs, 8 XCDs -> 32 consecutive logical tiles
  // per XCD; logical (m,n) = (swz>>2, swz&3) keeps an m-panel's 4 n-tiles
  // on one XCD for A-panel L2 reuse.
  const int orig = blockIdx.x;
  const int swz = (orig & 7) * 32 + (orig >> 3);
  const int m0 = (swz >> 2) * 256;
  const int n0 = (swz & 3) * 256;

  const int qm = (wid >> 2) * 64;  // wave row offset within a 128-row half
  const int qn = (wid & 3) * 32;   // wave col offset within a 128-col half
  const int lr = lane & 15;
  const int lq = lane >> 4;
  const int xr = lane & 7;         // == frag row & 7
  const int cs0 = (lq ^ xr) * 8;
  const int cs1 = ((4 + lq) ^ xr) * 8;
  const int aoff = (qm + lr) * 64;
  const int boff = (qn + lr) * 64;

  // staging: thread tid -> LDS elems [rl*64 + j8*8 .. +8), rl=tid>>3, j8=tid&7
  // global source chunk = j8 ^ (rl&7)  (swizzle via pre-permuted global addr)
  const int rl = tid >> 3;
  const int j8 = tid & 7;
  const int co = (j8 ^ (rl & 7)) * 8;
  const int lo = tid * 8;
  const ushort_t* gA = A + (size_t)(m0 + rl) * K + co;
  const ushort_t* gB = W + (size_t)(n0 + rl) * K + co;

  floatx4 acc[4][4][2] = {};  // [quadrant Mh*2+Nh][i][j]
  short8 atop[4][2], abot[4][2], b0E[2][2], b0O[2][2], b1[2][2];

  // prologue: stage tile0 -> buf0, publish, pre-read Q0 operands
  STAGE_A4(sA, 0);
  STAGE_B4(sB, 0);
  asm volatile("s_waitcnt vmcnt(0)" ::: "memory");
  BARSB;
  load_af(sA, aoff, cs0, cs1, atop);
  load_bf(sB, boff, cs0, cs1, b0E);

#pragma unroll 1
  for (int t = 0; t < NT; t += 2) {
    GROUP(t, 0, b0E, b0O);
    GROUP(t + 1, 1, b0O, b0E);
  }

  // ---- epilogue. C/D layout: col=lane&15, row=(lane>>4)*4+reg [m89] ----
  // acc quadrant q=(Mh*2+Nh): rows Mh*128+qm+i*16+rbase+r, cols Nh*128+qn+j*16+lr
  const int rbase = lq * 4;

  if constexpr (OUT32) {
    // fp32: 4 passes of 64 rows x 260-stride (1040B rows, 16B-aligned)
    float* sCf = (float*)smem;
#pragma unroll
    for (int p = 0; p < 4; p++) {
      if ((qm >> 6) == (p & 1)) {
#pragma unroll
        for (int Nh = 0; Nh < 2; Nh++)
#pragma unroll
          for (int j = 0; j < 2; j++) {
            const int col = Nh * 128 + qn + j * 16 + lr;
            const float bv = bias[n0 + col];
#pragma unroll
            for (int i = 0; i < 4; i++)
#pragma unroll
              for (int r = 0; r < 4; r++) {
                float v = acc[(p >> 1) * 2 + Nh][i][j][r] + bv;
                if (RELU) v = fmaxf(v, 0.0f);
                sCf[(i * 16 + rbase + r) * 260 + col] = v;
              }
          }
      }
      __syncthreads();
#pragma unroll
      for (int u = 0; u < 8; u++) {
        const int lin = u * 512 + tid;
        const int row = lin >> 6;
        const int c4 = (lin & 63) * 4;
        *(float4*)((float*)Cp + (size_t)(m0 + p * 64 + row) * N + n0 + c4) =
            *(const float4*)&sCf[row * 260 + c4];
      }
      __syncthreads();
    }
    return;
  }

  // bf16: 2 passes of 128 rows x 264-stride (528B rows, 16B-aligned,
  // +4-row groups rotate banks by 16 like the proven 136-stride layout)
  ushort_t* sC = smem;
#pragma unroll
  for (int p = 0; p < 2; p++) {
#pragma unroll
    for (int Nh = 0; Nh < 2; Nh++)
#pragma unroll
      for (int j = 0; j < 2; j++) {
        const int col = Nh * 128 + qn + j * 16 + lr;
        const float bv = bias[n0 + col];
#pragma unroll
        for (int i = 0; i < 4; i++)
#pragma unroll
          for (int r = 0; r < 4; r++) {
            float v = acc[p * 2 + Nh][i][j][r] + bv;
            if (RELU) v = fmaxf(v, 0.0f);
            sC[(qm + i * 16 + rbase + r) * 264 + col] = f2b(v);
          }
      }
    __syncthreads();
#pragma unroll
    for (int u = 0; u < 8; u++) {
      const int lin = u * 512 + tid;
      const int row = lin >> 5;
      const int c8 = (lin & 31) * 8;
      *(uint4*)((ushort_t*)Cp + (size_t)(m0 + p * 128 + row) * N + n0 + c8) =
          *(const uint4*)&sC[row * 264 + c8];
    }
    __syncthreads();
  }
}

// ---------------------------------------------------------------------------
// Per-token head-mix attention (bf16). One wave/token, 4 tokens/block.
// O may alias Q: all reads staged to LDS before any global write.
// ---------------------------------------------------------------------------
__global__ __launch_bounds__(256) void attn_kernel(
    const ushort_t* Q, const ushort_t* Kp, const ushort_t* Vp, ushort_t* O) {
  __shared__ __align__(16) ushort_t sq[4][1024];
  __shared__ __align__(16) ushort_t sk[4][1024];
  __shared__ __align__(16) ushort_t sv[4][1024];
  __shared__ float sp[4][64];

  const int t = threadIdx.x;
  const int w = t >> 6;
  const int lane = t & 63;
  const size_t base = ((size_t)blockIdx.x * 4 + w) * 1024;

  ((uint4*)sq[w])[lane] = ((const uint4*)(Q + base))[lane];
  ((uint4*)sq[w])[lane + 64] = ((const uint4*)(Q + base))[lane + 64];
  ((uint4*)sk[w])[lane] = ((const uint4*)(Kp + base))[lane];
  ((uint4*)sk[w])[lane + 64] = ((const uint4*)(Kp + base))[lane + 64];
  ((uint4*)sv[w])[lane] = ((const uint4*)(Vp + base))[lane];
  ((uint4*)sv[w])[lane + 64] = ((const uint4*)(Vp + base))[lane + 64];
  __syncthreads();

  {  // scores + softmax: lane = i*8 + j
    const int i = lane >> 3, j = lane & 7;
    const ushort_t* qr = &sq[w][i * 128];
    const ushort_t* kr = &sk[w][j * 128];
    float s = 0.0f;
#pragma unroll 16
    for (int h = 0; h < 128; h++) s += b2f(qr[h]) * b2f(kr[h]);
    s *= 0.08838834764831845f;  // 1/sqrt(128)
    float m = s;
#pragma unroll
    for (int off = 1; off < 8; off <<= 1) m = fmaxf(m, __shfl_xor(m, off, 64));
    float e = __expf(s - m);
    float sum = e;
#pragma unroll
    for (int off = 1; off < 8; off <<= 1) sum += __shfl_xor(sum, off, 64);
    sp[w][lane] = e / sum;
  }
  __syncthreads();

  {  // out[i][h] = sum_j P[i][j]*v[j][h]
    const int i = lane >> 3;
    const int hb = (lane & 7) * 16;
    float p[8];
#pragma unroll
    for (int jj = 0; jj < 8; jj++) p[jj] = sp[w][i * 8 + jj];
    float o[16];
#pragma unroll
    for (int h = 0; h < 16; h++) {
      float acc = 0.0f;
#pragma unroll
      for (int jj = 0; jj < 8; jj++) acc += p[jj] * b2f(sv[w][jj * 128 + hb + h]);
      o[h] = acc;
    }
    uint32_t packed[8];
#pragma unroll
    for (int u = 0; u < 8; u++)
      packed[u] = (uint32_t)f2b(o[2 * u]) | ((uint32_t)f2b(o[2 * u + 1]) << 16);
    uint4* dst = (uint4*)(O + base + i * 128 + hb);
    dst[0] = *(uint4*)&packed[0];
    dst[1] = *(uint4*)&packed[4];
  }
}

// ---------------------------------------------------------------------------
extern "C" void kernel_launch(void* const* d_in, const int* in_sizes, int n_in,
                              void* d_out, int out_size, void* d_ws, size_t ws_size,
                              hipStream_t stream) {
  const float* input_seq = (const float*)d_in[0];
  const float* output_seq = (const float*)d_in[1];
  const float* pe = (const float*)d_in[2];
  const float* wsrc[14] = {
      (const float*)d_in[3],  (const float*)d_in[5],  (const float*)d_in[7],
      (const float*)d_in[9],  (const float*)d_in[11], (const float*)d_in[13],
      (const float*)d_in[15], (const float*)d_in[17], (const float*)d_in[19],
      (const float*)d_in[21], (const float*)d_in[23], (const float*)d_in[25],
      (const float*)d_in[27], (const float*)d_in[29]};
  const float* enc_bq = (const float*)d_in[4];
  const float* enc_bk = (const float*)d_in[6];
  const float* enc_bv = (const float*)d_in[8];
  const float* enc_b1 = (const float*)d_in[10];
  const float* enc_b2 = (const float*)d_in[12];
  const float* dsq_b = (const float*)d_in[14];
  const float* dsk_b = (const float*)d_in[16];
  const float* dsv_b = (const float*)d_in[18];
  const float* dcq_b = (const float*)d_in[20];
  const float* dck_b = (const float*)d_in[22];
  const float* dcv_b = (const float*)d_in[24];
  const float* dec_b1 = (const float*)d_in[26];
  const float* dec_b2 = (const float*)d_in[28];
  const float* fc_b = (const float*)d_in[30];

  const size_t SZ = (size_t)TOKENS * DMODEL;   // 16.7M elems
  const size_t WSZ = (size_t)DMODEL * DMODEL;  // 1M elems
  ushort_t* bA = (ushort_t*)d_ws;        // 32MB
  ushort_t* bB = bA + SZ;                // 32MB
  ushort_t* oseq = bB + SZ;              // 32MB (output_seq in bf16)
  ushort_t* wts = oseq + SZ;             // 28MB bf16 weights
  ushort_t* oL = (ushort_t*)d_out;       // d_out lower 32MB as bf16 scratch
  ushort_t* oH = oL + SZ;                // d_out upper 32MB as bf16 scratch
  float* outf = (float*)d_out;

  // opt in to 128 KiB dynamic LDS (once per process)
  static bool attr_set = false;
  if (!attr_set) {
    (void)hipFuncSetAttribute(reinterpret_cast<const void*>(&gemm_bt<false, false>),
                              hipFuncAttributeMaxDynamicSharedMemorySize, 131072);
    (void)hipFuncSetAttribute(reinterpret_cast<const void*>(&gemm_bt<true, false>),
                              hipFuncAttributeMaxDynamicSharedMemorySize, 131072);
    (void)hipFuncSetAttribute(reinterpret_cast<const void*>(&gemm_bt<false, true>),
                              hipFuncAttributeMaxDynamicSharedMemorySize, 131072);
    attr_set = true;
  }

  // weight idx: 0 ewq,1 ewk,2 ewv,3 ew1,4 ew2,5 dsq,6 dsk,7 dsv,8 dcq,9 dck,
  //             10 dcv,11 dw1,12 dw2,13 fc
  ConvArgs ca;
#pragma unroll
  for (int i = 0; i < 14; i++) { ca.src[i] = wsrc[i]; ca.dst[i] = wts + (size_t)i * WSZ; }

  const dim3 gG(TOKENS / 256 * (DMODEL / 256));  // 64*4 = 256 wgs, 1/CU
  const dim3 gblk(512);
  const dim3 blk(256);
  const int LDSB = 131072;
  const int gPE = TOKENS * DMODEL / (256 * 8);  // 8192
  const int gAT = TOKENS / 4;                   // 4096

  conv_w_kernel<<<dim3(WSZ / (256 * 8), 14), blk, 0, stream>>>(ca);
  conv_x_kernel<<<gPE, blk, 0, stream>>>(output_seq, oseq);
  add_pe_kernel<<<gPE, blk, 0, stream>>>(input_seq, pe, bA);                   // bA = x
  // encoder self-attn
  gemm_bt<false, false><<<gG, gblk, LDSB, stream>>>(bA, wts + 0 * WSZ, enc_bq, bB);  // bB = q
  gemm_bt<false, false><<<gG, gblk, LDSB, stream>>>(bA, wts + 1 * WSZ, enc_bk, oL);  // oL = k
  gemm_bt<false, false><<<gG, gblk, LDSB, stream>>>(bA, wts + 2 * WSZ, enc_bv, oH);  // oH = v
  attn_kernel<<<gAT, blk, 0, stream>>>(bB, oL, oH, bB);                              // bB = a
  // encoder FFN
  gemm_bt<true, false><<<gG, gblk, LDSB, stream>>>(bB, wts + 3 * WSZ, enc_b1, bA);   // bA = h1
  gemm_bt<false, false><<<gG, gblk, LDSB, stream>>>(bA, wts + 4 * WSZ, enc_b2, bB);  // bB = enc_out
  // decoder self-attn
  gemm_bt<false, false><<<gG, gblk, LDSB, stream>>>(oseq, wts + 5 * WSZ, dsq_b, bA); // bA = q2
  gemm_bt<false, false><<<gG, gblk, LDSB, stream>>>(oseq, wts + 6 * WSZ, dsk_b, oL); // oL = k2
  gemm_bt<false, false><<<gG, gblk, LDSB, stream>>>(oseq, wts + 7 * WSZ, dsv_b, oH); // oH = v2
  attn_kernel<<<gAT, blk, 0, stream>>>(bA, oL, oH, bA);                              // bA = sa
  // decoder cross-attn (q from sa, k/v from enc_out)
  gemm_bt<false, false><<<gG, gblk, LDSB, stream>>>(bA, wts + 8 * WSZ, dcq_b, oL);   // oL = q3
  gemm_bt<false, false><<<gG, gblk, LDSB, stream>>>(bB, wts + 9 * WSZ, dck_b, oH);   // oH = k3
  gemm_bt<false, false><<<gG, gblk, LDSB, stream>>>(bB, wts + 10 * WSZ, dcv_b, bA);  // bA = v3
  attn_kernel<<<gAT, blk, 0, stream>>>(oL, oH, bA, oL);                              // oL = ca
  // decoder FFN + final fc
  gemm_bt<true, false><<<gG, gblk, LDSB, stream>>>(oL, wts + 11 * WSZ, dec_b1, bB);  // bB = h2
  gemm_bt<false, false><<<gG, gblk, LDSB, stream>>>(bB, wts + 12 * WSZ, dec_b2, bA); // bA = dec_out
  gemm_bt<false, true><<<gG, gblk, LDSB, stream>>>(bA, wts + 13 * WSZ, fc_b, outf);  // d_out fp32
}

// Round 8
// 836.240 us; speedup vs baseline: 1.2310x; 1.2310x over previous
//
#include <hip/hip_runtime.h>
#include <stdint.h>

// ---------------------------------------------------------------------------
// DialogueTransformer: B=8,S=2048,D=1024,H=8,HD=128 -> 16384 tokens, fp32 I/O.
// Round 12: GEMM core reverted to R8 (best measured: 2-region groups, 2
// barriers/K-tile, counted vmcnt(4), 42.2us/GEMM). R11's 4-phase pipeline
// regressed (61.5us) and is dropped. New: GEMMs sharing an A operand are
// FUSED into multi-output dispatches (weights are consecutive in wts, so the
// fused kernel is a wider-N GEMM over concatenated W with per-1024-col bias/
// output selection):
//   enc QKV   (A=x,      W=wts[0..2], N=3072, 768 wgs)
//   dec QKV   (A=oseq,   W=wts[5..7], N=3072, 768 wgs)
//   dec crossKV (A=enc_out, W=wts[9..10], N=2048, 512 wgs)
// Gains: A panel fetched once (L2-hot across an m-panel's n-tiles), 4 fewer
// launches, per-block inner loop byte-identical to R8.
// ws layout: bA(32MB) | bB(32MB) | oseq(32MB) | wts(28MB) = 124MB.
// d_out (64MB) doubles as two 32MB bf16 scratch halves until the final GEMM.
// ---------------------------------------------------------------------------

#define TOKENS 16384
#define DMODEL 1024

typedef unsigned short ushort_t;
typedef __attribute__((ext_vector_type(8))) short short8;
typedef __attribute__((ext_vector_type(4))) float floatx4;

__device__ __forceinline__ float b2f(ushort_t u) {
  union { uint32_t i; float f; } v; v.i = ((uint32_t)u) << 16; return v.f;
}
__device__ __forceinline__ ushort_t f2b(float f) {
  union { float f; uint32_t i; } v; v.f = f;
  uint32_t r = v.i + 0x7fffu + ((v.i >> 16) & 1u);
  return (ushort_t)(r >> 16);
}

// load 8 fp32 (16B-aligned), round to bf16, store 16B
__device__ __forceinline__ void pack8(const float* __restrict__ g, ushort_t* dst) {
  float4 x = *(const float4*)g;
  float4 y = *(const float4*)(g + 4);
  ushort_t o[8] = {f2b(x.x), f2b(x.y), f2b(x.z), f2b(x.w),
                   f2b(y.x), f2b(y.y), f2b(y.z), f2b(y.w)};
  *(uint4*)dst = *(uint4*)o;
}

// async global->LDS, 16B per lane (wave-uniform base + lane*16)
#define GLD16(g, l)                                                          \
  __builtin_amdgcn_global_load_lds(                                          \
      (const __attribute__((address_space(1))) void*)(g),                    \
      (__attribute__((address_space(3))) void*)(l), 16, 0, 0)

// ---------------------------------------------------------------------------
// weight pre-conversion: 14 matrices of 1024x1024 fp32 -> bf16
// ---------------------------------------------------------------------------
struct ConvArgs {
  const float* src[14];
  ushort_t* dst[14];
};

__global__ __launch_bounds__(256) void conv_w_kernel(ConvArgs a) {
  const int w = blockIdx.y;
  const int idx = (blockIdx.x * 256 + threadIdx.x) * 8;
  pack8(a.src[w] + idx, a.dst[w] + idx);
}

// generic fp32 -> bf16 conversion (output_seq)
__global__ __launch_bounds__(256) void conv_x_kernel(
    const float* __restrict__ src, ushort_t* __restrict__ dst) {
  const int idx = (blockIdx.x * 256 + threadIdx.x) * 8;
  pack8(src + idx, dst + idx);
}

// x = input + pe (fp32 in, bf16 out)
__global__ __launch_bounds__(256) void add_pe_kernel(
    const float* __restrict__ in, const float* __restrict__ pe,
    ushort_t* __restrict__ out) {
  int idx = (blockIdx.x * 256 + threadIdx.x) * 8;
  int d = idx & (DMODEL - 1);
  float4 a0 = *(const float4*)(in + idx);
  float4 a1 = *(const float4*)(in + idx + 4);
  float4 p0 = *(const float4*)(pe + d);
  float4 p1 = *(const float4*)(pe + d + 4);
  ushort_t o[8] = {f2b(a0.x + p0.x), f2b(a0.y + p0.y), f2b(a0.z + p0.z), f2b(a0.w + p0.w),
                   f2b(a1.x + p1.x), f2b(a1.y + p1.y), f2b(a1.z + p1.z), f2b(a1.w + p1.w)};
  *(uint4*)(out + idx) = *(uint4*)o;
}

// ---------------------------------------------------------------------------
// GEMM helpers (R8 core). LDS layout per buffer d in {0,1}:
//   sA + d*16384 : A tile [256 rows][64 cols] bf16 (top half rows 0-127)
//   sB + d*16384 : B tile [256 rows][64 cols] bf16
// LDS slot (row, chunk j) holds global chunk j^(row&7) (16B chunks) -- the
// proven conflict-free swizzle (pre-swizzled GLOBAL source; LDS dest linear,
// as global_load_lds requires). Frag read chunk = (kk*4+lq)^(row&7).
// ---------------------------------------------------------------------------
template <int D, int MH>
__device__ __forceinline__ void load_a(const ushort_t* sA, int aoff, int cs0,
                                       int cs1, short8 (&af)[4][2]) {
  const ushort_t* p = sA + D * 16384 + MH * 8192 + aoff;
#pragma unroll
  for (int i = 0; i < 4; i++) {
    af[i][0] = *(const short8*)&p[i * 1024 + cs0];
    af[i][1] = *(const short8*)&p[i * 1024 + cs1];
  }
}

template <int D, int NH>
__device__ __forceinline__ void load_b(const ushort_t* sB, int boff, int cs0,
                                       int cs1, short8 (&bf)[2][2]) {
  const ushort_t* p = sB + D * 16384 + NH * 8192 + boff;
#pragma unroll
  for (int j = 0; j < 2; j++) {
    bf[j][0] = *(const short8*)&p[j * 1024 + cs0];
    bf[j][1] = *(const short8*)&p[j * 1024 + cs1];
  }
}

// two C-quadrants x K=64: 32 MFMA, setprio-wrapped (T5)
template <int QA, int QB>
__device__ __forceinline__ void mfma_region(floatx4 (&acc)[4][4][2],
                                            const short8 (&af)[4][2],
                                            const short8 (&b0)[2][2],
                                            const short8 (&b1)[2][2]) {
  __builtin_amdgcn_s_setprio(1);
#pragma unroll
  for (int i = 0; i < 4; i++)
#pragma unroll
    for (int j = 0; j < 2; j++) {
      acc[QA][i][j] = __builtin_amdgcn_mfma_f32_16x16x32_bf16(
          af[i][0], b0[j][0], acc[QA][i][j], 0, 0, 0);
      acc[QA][i][j] = __builtin_amdgcn_mfma_f32_16x16x32_bf16(
          af[i][1], b0[j][1], acc[QA][i][j], 0, 0, 0);
    }
#pragma unroll
  for (int i = 0; i < 4; i++)
#pragma unroll
    for (int j = 0; j < 2; j++) {
      acc[QB][i][j] = __builtin_amdgcn_mfma_f32_16x16x32_bf16(
          af[i][0], b1[j][0], acc[QB][i][j], 0, 0, 0);
      acc[QB][i][j] = __builtin_amdgcn_mfma_f32_16x16x32_bf16(
          af[i][1], b1[j][1], acc[QB][i][j], 0, 0, 0);
    }
  __builtin_amdgcn_s_setprio(0);
}

// builtin barrier (no compiler memory drain) pinned on both sides so loads
// cannot migrate across it at the machine level
#define BARRIER_PINNED                                                       \
  do {                                                                       \
    __builtin_amdgcn_sched_barrier(0);                                       \
    __builtin_amdgcn_s_barrier();                                            \
    __builtin_amdgcn_sched_barrier(0);                                       \
  } while (0)

// stage one 128-row half-tile (h=0 top / h=1 bottom) of K-tile tk into buf d.
// 2 x GLD16 per thread; LDS dest linear in tid (wave-uniform base + lane*16).
#define STAGE_A(h, tk, d)                                                    \
  do {                                                                       \
    GLD16(gA + (size_t)((h) * 131072 + (tk) * 64),                           \
          sA + (d) * 16384 + (h) * 8192 + lo);                               \
    GLD16(gA + (size_t)((h) * 131072 + 65536 + (tk) * 64),                   \
          sA + (d) * 16384 + (h) * 8192 + 4096 + lo);                        \
  } while (0)
#define STAGE_B(h, tk, d)                                                    \
  do {                                                                       \
    GLD16(gB + (size_t)((h) * 131072 + (tk) * 64),                           \
          sB + (d) * 16384 + (h) * 8192 + lo);                               \
    GLD16(gB + (size_t)((h) * 131072 + 65536 + (tk) * 64),                   \
          sB + (d) * 16384 + (h) * 8192 + 4096 + lo);                        \
  } while (0)

// one K-tile = 2 regions (R8 sync ledger):
//   region1: read A-top,B-top,B-bot(dd); stage late-half(t+1)->dd^1;
//            MFMA Q0,Q1; lgkmcnt(0)+pin; BARRIER   (all reads of dd done)
//   region2: read A-bot(dd); stage early-half(t+2)->dd;
//            MFMA Q2,Q3; vmcnt(4)+lgkmcnt(0)+pin; BARRIER (tile t+1 ready)
#define GROUP(tt, dd)                                                        \
  do {                                                                       \
    load_a<dd, 0>(sA, aoff, cs0, cs1, af);                                   \
    load_b<dd, 0>(sB, boff, cs0, cs1, bf0);                                  \
    load_b<dd, 1>(sB, boff, cs0, cs1, bf1);                                  \
    if ((tt) + 1 < NT) {                                                     \
      STAGE_B(0, (tt) + 1, (dd) ^ 1);                                        \
      STAGE_A(1, (tt) + 1, (dd) ^ 1);                                        \
    }                                                                        \
    mfma_region<0, 1>(acc, af, bf0, bf1);                                    \
    asm volatile("s_waitcnt lgkmcnt(0)");                                    \
    BARRIER_PINNED;                                                          \
    load_a<dd, 1>(sA, aoff, cs0, cs1, af);                                   \
    if ((tt) + 2 < NT) {                                                     \
      STAGE_A(0, (tt) + 2, dd);                                              \
      STAGE_B(1, (tt) + 2, dd);                                              \
    }                                                                        \
    mfma_region<2, 3>(acc, af, bf0, bf1);                                    \
    if ((tt) + 2 < NT)                                                       \
      asm volatile("s_waitcnt vmcnt(4) lgkmcnt(0)");                         \
    else if ((tt) + 1 < NT)                                                  \
      asm volatile("s_waitcnt vmcnt(0) lgkmcnt(0)");                         \
    else                                                                     \
      asm volatile("s_waitcnt lgkmcnt(0)");                                  \
    BARRIER_PINNED;                                                          \
  } while (0)

// shared K-loop body macro (identical for single and multi variants)
#define GEMM_PREAMBLE_AND_LOOP                                               \
  const int qm = (wid >> 2) * 64;                                            \
  const int qn = (wid & 3) * 32;                                             \
  const int lr = lane & 15;                                                  \
  const int lq = lane >> 4;                                                  \
  const int xr = lane & 7;                                                   \
  const int cs0 = (lq ^ xr) * 8;                                             \
  const int cs1 = ((4 + lq) ^ xr) * 8;                                       \
  const int aoff = (qm + lr) * 64;                                           \
  const int boff = (qn + lr) * 64;                                           \
  const int rl = tid >> 3;                                                   \
  const int j8 = tid & 7;                                                    \
  const int co = (j8 ^ (rl & 7)) * 8;                                        \
  const int lo = tid * 8;                                                    \
  const ushort_t* gA = A + (size_t)(m0 + rl) * K + co;                       \
  const ushort_t* gB = W + (size_t)(n0 + rl) * K + co;                       \
  floatx4 acc[4][4][2] = {};                                                 \
  short8 af[4][2], bf0[2][2], bf1[2][2];                                     \
  STAGE_A(0, 0, 0);                                                          \
  STAGE_B(1, 0, 0);                                                          \
  STAGE_B(0, 0, 0);                                                          \
  STAGE_A(1, 0, 0);                                                          \
  STAGE_A(0, 1, 1);                                                          \
  STAGE_B(1, 1, 1);                                                          \
  asm volatile("s_waitcnt vmcnt(4)");                                        \
  BARRIER_PINNED;                                                            \
  _Pragma("unroll 1")                                                        \
  for (int t = 0; t < NT; t += 2) {                                          \
    GROUP(t, 0);                                                             \
    GROUP(t + 1, 1);                                                         \
  }

// ---------------------------------------------------------------------------
// Single-output GEMM: C[t,n] = sum_k A[t,k]*W[n,k] + bias[n].
// M=16384, N=K=1024. 256x256 tile, 8 waves, 2x4 per-quadrant wave split.
// ---------------------------------------------------------------------------
template <bool RELU, bool OUT32>
__global__ __launch_bounds__(512, 2) void gemm_bt(
    const ushort_t* __restrict__ A, const ushort_t* __restrict__ W,
    const float* __restrict__ bias, void* __restrict__ Cp) {
  constexpr int K = 1024, N = 1024, NT = 16;
  extern __shared__ ushort_t smem[];
  ushort_t* sA = smem;
  ushort_t* sB = smem + 32768;

  const int tid = threadIdx.x;
  const int lane = tid & 63;
  const int wid = tid >> 6;

  // XCD-bijective swizzle: 256 wgs -> 32/XCD; m-panel's 4 n-tiles grouped.
  const int orig = blockIdx.x;
  const int swz = (orig & 7) * 32 + (orig >> 3);
  const int m0 = (swz >> 2) * 256;
  const int n0 = (swz & 3) * 256;

  GEMM_PREAMBLE_AND_LOOP;

  // ---- epilogue. C/D layout: col=lane&15, row=(lane>>4)*4+reg [m89] ----
  const int rbase = lq * 4;

  if constexpr (OUT32) {
    float* sCf = (float*)smem;
#pragma unroll
    for (int p = 0; p < 4; p++) {
      if ((qm >> 6) == (p & 1)) {
#pragma unroll
        for (int Nh = 0; Nh < 2; Nh++)
#pragma unroll
          for (int j = 0; j < 2; j++) {
            const int col = Nh * 128 + qn + j * 16 + lr;
            const float bv = bias[n0 + col];
#pragma unroll
            for (int i = 0; i < 4; i++)
#pragma unroll
              for (int r = 0; r < 4; r++) {
                float v = acc[(p >> 1) * 2 + Nh][i][j][r] + bv;
                if (RELU) v = fmaxf(v, 0.0f);
                sCf[(i * 16 + rbase + r) * 260 + col] = v;
              }
          }
      }
      __syncthreads();
#pragma unroll
      for (int u = 0; u < 8; u++) {
        const int lin = u * 512 + tid;
        const int row = lin >> 6;
        const int c4 = (lin & 63) * 4;
        *(float4*)((float*)Cp + (size_t)(m0 + p * 64 + row) * N + n0 + c4) =
            *(const float4*)&sCf[row * 260 + c4];
      }
      __syncthreads();
    }
    return;
  }

  ushort_t* sC = smem;
#pragma unroll
  for (int p = 0; p < 2; p++) {
#pragma unroll
    for (int Nh = 0; Nh < 2; Nh++)
#pragma unroll
      for (int j = 0; j < 2; j++) {
        const int col = Nh * 128 + qn + j * 16 + lr;
        const float bv = bias[n0 + col];
#pragma unroll
        for (int i = 0; i < 4; i++)
#pragma unroll
          for (int r = 0; r < 4; r++) {
            float v = acc[p * 2 + Nh][i][j][r] + bv;
            if (RELU) v = fmaxf(v, 0.0f);
            sC[(qm + i * 16 + rbase + r) * 264 + col] = f2b(v);
          }
      }
    __syncthreads();
#pragma unroll
    for (int u = 0; u < 8; u++) {
      const int lin = u * 512 + tid;
      const int row = lin >> 5;
      const int c8 = (lin & 31) * 8;
      *(uint4*)((ushort_t*)Cp + (size_t)(m0 + p * 128 + row) * N + n0 + c8) =
          *(const uint4*)&sC[row * 264 + c8];
    }
    __syncthreads();
  }
}

// ---------------------------------------------------------------------------
// Multi-output GEMM: NMAT consecutive 1024x1024 weight matrices treated as
// one (NMAT*1024)-row W; per-1024-col range selects bias/output pointer.
// Inner loop byte-identical to gemm_bt. bf16 out only, no relu.
// ---------------------------------------------------------------------------
struct MultiOut {
  const float* bias[3];
  ushort_t* out[3];
};

template <int NMAT>
__global__ __launch_bounds__(512, 2) void gemm_bt_multi(
    const ushort_t* __restrict__ A, const ushort_t* __restrict__ W,
    MultiOut mo) {
  constexpr int K = 1024, N = 1024, NT = 16;
  constexpr int NB = NMAT * 4;          // 256-col tiles across fused N
  constexpr int CPX = (64 * NB) / 8;    // wgs per XCD (nwg % 8 == 0)
  extern __shared__ ushort_t smem[];
  ushort_t* sA = smem;
  ushort_t* sB = smem + 32768;

  const int tid = threadIdx.x;
  const int lane = tid & 63;
  const int wid = tid >> 6;

  const int orig = blockIdx.x;
  const int swz = (orig & 7) * CPX + (orig >> 3);
  const int m0 = (swz / NB) * 256;
  const int nn = swz % NB;              // m-panel's NB n-tiles contiguous
  const int n0 = nn * 256;              // row into concatenated W
  const int which = nn >> 2;
  const int nloc = (nn & 3) * 256;      // col offset within the output matrix

  GEMM_PREAMBLE_AND_LOOP;

  const int rbase = lq * 4;
  const float* bias = mo.bias[which];
  ushort_t* Cb = mo.out[which];

  ushort_t* sC = smem;
#pragma unroll
  for (int p = 0; p < 2; p++) {
#pragma unroll
    for (int Nh = 0; Nh < 2; Nh++)
#pragma unroll
      for (int j = 0; j < 2; j++) {
        const int col = Nh * 128 + qn + j * 16 + lr;
        const float bv = bias[nloc + col];
#pragma unroll
        for (int i = 0; i < 4; i++)
#pragma unroll
          for (int r = 0; r < 4; r++) {
            float v = acc[p * 2 + Nh][i][j][r] + bv;
            sC[(qm + i * 16 + rbase + r) * 264 + col] = f2b(v);
          }
      }
    __syncthreads();
#pragma unroll
    for (int u = 0; u < 8; u++) {
      const int lin = u * 512 + tid;
      const int row = lin >> 5;
      const int c8 = (lin & 31) * 8;
      *(uint4*)(Cb + (size_t)(m0 + p * 128 + row) * N + nloc + c8) =
          *(const uint4*)&sC[row * 264 + c8];
    }
    __syncthreads();
  }
}

// ---------------------------------------------------------------------------
// Per-token head-mix attention (bf16). One wave/token, 4 tokens/block.
// O may alias Q: all reads staged to LDS before any global write.
// ---------------------------------------------------------------------------
__global__ __launch_bounds__(256) void attn_kernel(
    const ushort_t* Q, const ushort_t* Kp, const ushort_t* Vp, ushort_t* O) {
  __shared__ __align__(16) ushort_t sq[4][1024];
  __shared__ __align__(16) ushort_t sk[4][1024];
  __shared__ __align__(16) ushort_t sv[4][1024];
  __shared__ float sp[4][64];

  const int t = threadIdx.x;
  const int w = t >> 6;
  const int lane = t & 63;
  const size_t base = ((size_t)blockIdx.x * 4 + w) * 1024;

  ((uint4*)sq[w])[lane] = ((const uint4*)(Q + base))[lane];
  ((uint4*)sq[w])[lane + 64] = ((const uint4*)(Q + base))[lane + 64];
  ((uint4*)sk[w])[lane] = ((const uint4*)(Kp + base))[lane];
  ((uint4*)sk[w])[lane + 64] = ((const uint4*)(Kp + base))[lane + 64];
  ((uint4*)sv[w])[lane] = ((const uint4*)(Vp + base))[lane];
  ((uint4*)sv[w])[lane + 64] = ((const uint4*)(Vp + base))[lane + 64];
  __syncthreads();

  {  // scores + softmax: lane = i*8 + j
    const int i = lane >> 3, j = lane & 7;
    const ushort_t* qr = &sq[w][i * 128];
    const ushort_t* kr = &sk[w][j * 128];
    float s = 0.0f;
#pragma unroll 16
    for (int h = 0; h < 128; h++) s += b2f(qr[h]) * b2f(kr[h]);
    s *= 0.08838834764831845f;  // 1/sqrt(128)
    float m = s;
#pragma unroll
    for (int off = 1; off < 8; off <<= 1) m = fmaxf(m, __shfl_xor(m, off, 64));
    float e = __expf(s - m);
    float sum = e;
#pragma unroll
    for (int off = 1; off < 8; off <<= 1) sum += __shfl_xor(sum, off, 64);
    sp[w][lane] = e / sum;
  }
  __syncthreads();

  {  // out[i][h] = sum_j P[i][j]*v[j][h]
    const int i = lane >> 3;
    const int hb = (lane & 7) * 16;
    float p[8];
#pragma unroll
    for (int jj = 0; jj < 8; jj++) p[jj] = sp[w][i * 8 + jj];
    float o[16];
#pragma unroll
    for (int h = 0; h < 16; h++) {
      float acc = 0.0f;
#pragma unroll
      for (int jj = 0; jj < 8; jj++) acc += p[jj] * b2f(sv[w][jj * 128 + hb + h]);
      o[h] = acc;
    }
    uint32_t packed[8];
#pragma unroll
    for (int u = 0; u < 8; u++)
      packed[u] = (uint32_t)f2b(o[2 * u]) | ((uint32_t)f2b(o[2 * u + 1]) << 16);
    uint4* dst = (uint4*)(O + base + i * 128 + hb);
    dst[0] = *(uint4*)&packed[0];
    dst[1] = *(uint4*)&packed[4];
  }
}

// ---------------------------------------------------------------------------
extern "C" void kernel_launch(void* const* d_in, const int* in_sizes, int n_in,
                              void* d_out, int out_size, void* d_ws, size_t ws_size,
                              hipStream_t stream) {
  const float* input_seq = (const float*)d_in[0];
  const float* output_seq = (const float*)d_in[1];
  const float* pe = (const float*)d_in[2];
  const float* wsrc[14] = {
      (const float*)d_in[3],  (const float*)d_in[5],  (const float*)d_in[7],
      (const float*)d_in[9],  (const float*)d_in[11], (const float*)d_in[13],
      (const float*)d_in[15], (const float*)d_in[17], (const float*)d_in[19],
      (const float*)d_in[21], (const float*)d_in[23], (const float*)d_in[25],
      (const float*)d_in[27], (const float*)d_in[29]};
  const float* enc_bq = (const float*)d_in[4];
  const float* enc_bk = (const float*)d_in[6];
  const float* enc_bv = (const float*)d_in[8];
  const float* enc_b1 = (const float*)d_in[10];
  const float* enc_b2 = (const float*)d_in[12];
  const float* dsq_b = (const float*)d_in[14];
  const float* dsk_b = (const float*)d_in[16];
  const float* dsv_b = (const float*)d_in[18];
  const float* dcq_b = (const float*)d_in[20];
  const float* dck_b = (const float*)d_in[22];
  const float* dcv_b = (const float*)d_in[24];
  const float* dec_b1 = (const float*)d_in[26];
  const float* dec_b2 = (const float*)d_in[28];
  const float* fc_b = (const float*)d_in[30];

  const size_t SZ = (size_t)TOKENS * DMODEL;   // 16.7M elems
  const size_t WSZ = (size_t)DMODEL * DMODEL;  // 1M elems
  ushort_t* bA = (ushort_t*)d_ws;        // 32MB
  ushort_t* bB = bA + SZ;                // 32MB
  ushort_t* oseq = bB + SZ;              // 32MB (output_seq in bf16)
  ushort_t* wts = oseq + SZ;             // 28MB bf16 weights
  ushort_t* oL = (ushort_t*)d_out;       // d_out lower 32MB as bf16 scratch
  ushort_t* oH = oL + SZ;                // d_out upper 32MB as bf16 scratch
  float* outf = (float*)d_out;

  // opt in to 128 KiB dynamic LDS (once per process)
  static bool attr_set = false;
  if (!attr_set) {
    (void)hipFuncSetAttribute(reinterpret_cast<const void*>(&gemm_bt<false, false>),
                              hipFuncAttributeMaxDynamicSharedMemorySize, 131072);
    (void)hipFuncSetAttribute(reinterpret_cast<const void*>(&gemm_bt<true, false>),
                              hipFuncAttributeMaxDynamicSharedMemorySize, 131072);
    (void)hipFuncSetAttribute(reinterpret_cast<const void*>(&gemm_bt<false, true>),
                              hipFuncAttributeMaxDynamicSharedMemorySize, 131072);
    (void)hipFuncSetAttribute(reinterpret_cast<const void*>(&gemm_bt_multi<3>),
                              hipFuncAttributeMaxDynamicSharedMemorySize, 131072);
    (void)hipFuncSetAttribute(reinterpret_cast<const void*>(&gemm_bt_multi<2>),
                              hipFuncAttributeMaxDynamicSharedMemorySize, 131072);
    attr_set = true;
  }

  // weight idx: 0 ewq,1 ewk,2 ewv,3 ew1,4 ew2,5 dsq,6 dsk,7 dsv,8 dcq,9 dck,
  //             10 dcv,11 dw1,12 dw2,13 fc
  ConvArgs ca;
#pragma unroll
  for (int i = 0; i < 14; i++) { ca.src[i] = wsrc[i]; ca.dst[i] = wts + (size_t)i * WSZ; }

  const dim3 gG(TOKENS / 256 * (DMODEL / 256));  // 256 wgs
  const dim3 gG3(TOKENS / 256 * 12);             // 768 wgs (NMAT=3)
  const dim3 gG2(TOKENS / 256 * 8);              // 512 wgs (NMAT=2)
  const dim3 gblk(512);
  const dim3 blk(256);
  const int LDSB = 131072;
  const int gPE = TOKENS * DMODEL / (256 * 8);  // 8192
  const int gAT = TOKENS / 4;                   // 4096

  conv_w_kernel<<<dim3(WSZ / (256 * 8), 14), blk, 0, stream>>>(ca);
  conv_x_kernel<<<gPE, blk, 0, stream>>>(output_seq, oseq);
  add_pe_kernel<<<gPE, blk, 0, stream>>>(input_seq, pe, bA);                   // bA = x

  // encoder self-attn: fused QKV (W 0..2 consecutive)
  MultiOut eqkv = {{enc_bq, enc_bk, enc_bv}, {bB, oL, oH}};
  gemm_bt_multi<3><<<gG3, gblk, LDSB, stream>>>(bA, wts + 0 * WSZ, eqkv);
  attn_kernel<<<gAT, blk, 0, stream>>>(bB, oL, oH, bB);                        // bB = a
  // encoder FFN
  gemm_bt<true, false><<<gG, gblk, LDSB, stream>>>(bB, wts + 3 * WSZ, enc_b1, bA);   // bA = h1
  gemm_bt<false, false><<<gG, gblk, LDSB, stream>>>(bA, wts + 4 * WSZ, enc_b2, bB);  // bB = enc_out
  // decoder self-attn: fused QKV (W 5..7 consecutive)
  MultiOut dqkv = {{dsq_b, dsk_b, dsv_b}, {bA, oL, oH}};
  gemm_bt_multi<3><<<gG3, gblk, LDSB, stream>>>(oseq, wts + 5 * WSZ, dqkv);
  attn_kernel<<<gAT, blk, 0, stream>>>(bA, oL, oH, bA);                        // bA = sa
  // decoder cross-attn: q from sa; fused K/V from enc_out (W 9..10)
  gemm_bt<false, false><<<gG, gblk, LDSB, stream>>>(bA, wts + 8 * WSZ, dcq_b, oL);   // oL = q3
  MultiOut dkv = {{dck_b, dcv_b, nullptr}, {oH, bA, nullptr}};
  gemm_bt_multi<2><<<gG2, gblk, LDSB, stream>>>(bB, wts + 9 * WSZ, dkv);       // oH = k3, bA = v3
  attn_kernel<<<gAT, blk, 0, stream>>>(oL, oH, bA, oL);                        // oL = ca
  // decoder FFN + final fc
  gemm_bt<true, false><<<gG, gblk, LDSB, stream>>>(oL, wts + 11 * WSZ, dec_b1, bB);  // bB = h2
  gemm_bt<false, false><<<gG, gblk, LDSB, stream>>>(bB, wts + 12 * WSZ, dec_b2, bA); // bA = dec_out
  gemm_bt<false, true><<<gG, gblk, LDSB, stream>>>(bA, wts + 13 * WSZ, fc_b, outf);  // d_out fp32
}

// Round 9
// 822.867 us; speedup vs baseline: 1.2510x; 1.0163x over previous
//
#include <hip/hip_runtime.h>
#include <stdint.h>

// ---------------------------------------------------------------------------
// DialogueTransformer: B=8,S=2048,D=1024,H=8,HD=128 -> 16384 tokens, fp32 I/O.
// Round 13: dispatch-count consolidation on top of R12. Evidence (R8 bench):
// fused multi-GEMM = 36us/GEMM-equiv @ MfmaUtil 40% vs 42.2us @ 28% single
// -> ~11us fixed cost per dispatch. This round:
//   1. conv_w(14) + conv_x + add_pe merged into ONE preproc dispatch.
//   2. dcq + dcKV merged into one 3-matrix multi (per-matrix A pointers;
//      v3 routed to oseq [dead after decQKV] to fix the R12 write/read race).
//   3. Multi kernel carries Asrc[3] (QKV fusions pass same A x3).
// GEMM core = R8 (2-region, 2 barriers/K-tile, counted vmcnt(4)) unchanged.
// Dispatches 15 -> 12.
// ws layout: bA(32MB) | bB(32MB) | oseq(32MB) | wts(28MB) = 124MB.
// d_out (64MB) doubles as two 32MB bf16 scratch halves until the final GEMM.
// ---------------------------------------------------------------------------

#define TOKENS 16384
#define DMODEL 1024

typedef unsigned short ushort_t;
typedef __attribute__((ext_vector_type(8))) short short8;
typedef __attribute__((ext_vector_type(4))) float floatx4;

__device__ __forceinline__ float b2f(ushort_t u) {
  union { uint32_t i; float f; } v; v.i = ((uint32_t)u) << 16; return v.f;
}
__device__ __forceinline__ ushort_t f2b(float f) {
  union { float f; uint32_t i; } v; v.f = f;
  uint32_t r = v.i + 0x7fffu + ((v.i >> 16) & 1u);
  return (ushort_t)(r >> 16);
}

// load 8 fp32 (16B-aligned), round to bf16, store 16B
__device__ __forceinline__ void pack8(const float* __restrict__ g, ushort_t* dst) {
  float4 x = *(const float4*)g;
  float4 y = *(const float4*)(g + 4);
  ushort_t o[8] = {f2b(x.x), f2b(x.y), f2b(x.z), f2b(x.w),
                   f2b(y.x), f2b(y.y), f2b(y.z), f2b(y.w)};
  *(uint4*)dst = *(uint4*)o;
}

// async global->LDS, 16B per lane (wave-uniform base + lane*16)
#define GLD16(g, l)                                                          \
  __builtin_amdgcn_global_load_lds(                                          \
      (const __attribute__((address_space(1))) void*)(g),                    \
      (__attribute__((address_space(3))) void*)(l), 16, 0, 0)

// ---------------------------------------------------------------------------
// merged preprocessing: 14x weight conv (512 blocks each) + oseq conv (8192)
// + add_pe (8192). 23552 blocks, branch is uniform per block.
// ---------------------------------------------------------------------------
struct PreArgs {
  const float* wsrc[14];
  ushort_t* wdst;             // wts base (14 x 1M elems)
  const float* oseq_src;
  ushort_t* oseq_dst;
  const float* in_seq;
  const float* pe;
  ushort_t* x_dst;
};

__global__ __launch_bounds__(256) void preproc_kernel(PreArgs a) {
  const int b = blockIdx.x;
  if (b < 14 * 512) {
    const int w = b >> 9;
    const int idx = ((b & 511) * 256 + threadIdx.x) * 8;
    pack8(a.wsrc[w] + idx, a.wdst + (size_t)w * (DMODEL * DMODEL) + idx);
  } else if (b < 14 * 512 + 8192) {
    const int idx = ((b - 14 * 512) * 256 + threadIdx.x) * 8;
    pack8(a.oseq_src + idx, a.oseq_dst + idx);
  } else {
    const int idx = ((b - 14 * 512 - 8192) * 256 + threadIdx.x) * 8;
    const int d = idx & (DMODEL - 1);
    float4 a0 = *(const float4*)(a.in_seq + idx);
    float4 a1 = *(const float4*)(a.in_seq + idx + 4);
    float4 p0 = *(const float4*)(a.pe + d);
    float4 p1 = *(const float4*)(a.pe + d + 4);
    ushort_t o[8] = {f2b(a0.x + p0.x), f2b(a0.y + p0.y), f2b(a0.z + p0.z), f2b(a0.w + p0.w),
                     f2b(a1.x + p1.x), f2b(a1.y + p1.y), f2b(a1.z + p1.z), f2b(a1.w + p1.w)};
    *(uint4*)(a.x_dst + idx) = *(uint4*)o;
  }
}

// ---------------------------------------------------------------------------
// GEMM helpers (R8 core). LDS layout per buffer d in {0,1}:
//   sA + d*16384 : A tile [256 rows][64 cols] bf16 (top half rows 0-127)
//   sB + d*16384 : B tile [256 rows][64 cols] bf16
// LDS slot (row, chunk j) holds global chunk j^(row&7) (16B chunks) -- the
// proven conflict-free swizzle (pre-swizzled GLOBAL source; LDS dest linear,
// as global_load_lds requires). Frag read chunk = (kk*4+lq)^(row&7).
// ---------------------------------------------------------------------------
template <int D, int MH>
__device__ __forceinline__ void load_a(const ushort_t* sA, int aoff, int cs0,
                                       int cs1, short8 (&af)[4][2]) {
  const ushort_t* p = sA + D * 16384 + MH * 8192 + aoff;
#pragma unroll
  for (int i = 0; i < 4; i++) {
    af[i][0] = *(const short8*)&p[i * 1024 + cs0];
    af[i][1] = *(const short8*)&p[i * 1024 + cs1];
  }
}

template <int D, int NH>
__device__ __forceinline__ void load_b(const ushort_t* sB, int boff, int cs0,
                                       int cs1, short8 (&bf)[2][2]) {
  const ushort_t* p = sB + D * 16384 + NH * 8192 + boff;
#pragma unroll
  for (int j = 0; j < 2; j++) {
    bf[j][0] = *(const short8*)&p[j * 1024 + cs0];
    bf[j][1] = *(const short8*)&p[j * 1024 + cs1];
  }
}

// two C-quadrants x K=64: 32 MFMA, setprio-wrapped (T5)
template <int QA, int QB>
__device__ __forceinline__ void mfma_region(floatx4 (&acc)[4][4][2],
                                            const short8 (&af)[4][2],
                                            const short8 (&b0)[2][2],
                                            const short8 (&b1)[2][2]) {
  __builtin_amdgcn_s_setprio(1);
#pragma unroll
  for (int i = 0; i < 4; i++)
#pragma unroll
    for (int j = 0; j < 2; j++) {
      acc[QA][i][j] = __builtin_amdgcn_mfma_f32_16x16x32_bf16(
          af[i][0], b0[j][0], acc[QA][i][j], 0, 0, 0);
      acc[QA][i][j] = __builtin_amdgcn_mfma_f32_16x16x32_bf16(
          af[i][1], b0[j][1], acc[QA][i][j], 0, 0, 0);
    }
#pragma unroll
  for (int i = 0; i < 4; i++)
#pragma unroll
    for (int j = 0; j < 2; j++) {
      acc[QB][i][j] = __builtin_amdgcn_mfma_f32_16x16x32_bf16(
          af[i][0], b1[j][0], acc[QB][i][j], 0, 0, 0);
      acc[QB][i][j] = __builtin_amdgcn_mfma_f32_16x16x32_bf16(
          af[i][1], b1[j][1], acc[QB][i][j], 0, 0, 0);
    }
  __builtin_amdgcn_s_setprio(0);
}

// builtin barrier (no compiler memory drain) pinned on both sides so loads
// cannot migrate across it at the machine level
#define BARRIER_PINNED                                                       \
  do {                                                                       \
    __builtin_amdgcn_sched_barrier(0);                                       \
    __builtin_amdgcn_s_barrier();                                            \
    __builtin_amdgcn_sched_barrier(0);                                       \
  } while (0)

// stage one 128-row half-tile (h=0 top / h=1 bottom) of K-tile tk into buf d.
// 2 x GLD16 per thread; LDS dest linear in tid (wave-uniform base + lane*16).
#define STAGE_A(h, tk, d)                                                    \
  do {                                                                       \
    GLD16(gA + (size_t)((h) * 131072 + (tk) * 64),                           \
          sA + (d) * 16384 + (h) * 8192 + lo);                               \
    GLD16(gA + (size_t)((h) * 131072 + 65536 + (tk) * 64),                   \
          sA + (d) * 16384 + (h) * 8192 + 4096 + lo);                        \
  } while (0)
#define STAGE_B(h, tk, d)                                                    \
  do {                                                                       \
    GLD16(gB + (size_t)((h) * 131072 + (tk) * 64),                           \
          sB + (d) * 16384 + (h) * 8192 + lo);                               \
    GLD16(gB + (size_t)((h) * 131072 + 65536 + (tk) * 64),                   \
          sB + (d) * 16384 + (h) * 8192 + 4096 + lo);                        \
  } while (0)

// one K-tile = 2 regions (R8 sync ledger):
//   region1: read A-top,B-top,B-bot(dd); stage late-half(t+1)->dd^1;
//            MFMA Q0,Q1; lgkmcnt(0)+pin; BARRIER   (all reads of dd done)
//   region2: read A-bot(dd); stage early-half(t+2)->dd;
//            MFMA Q2,Q3; vmcnt(4)+lgkmcnt(0)+pin; BARRIER (tile t+1 ready)
#define GROUP(tt, dd)                                                        \
  do {                                                                       \
    load_a<dd, 0>(sA, aoff, cs0, cs1, af);                                   \
    load_b<dd, 0>(sB, boff, cs0, cs1, bf0);                                  \
    load_b<dd, 1>(sB, boff, cs0, cs1, bf1);                                  \
    if ((tt) + 1 < NT) {                                                     \
      STAGE_B(0, (tt) + 1, (dd) ^ 1);                                        \
      STAGE_A(1, (tt) + 1, (dd) ^ 1);                                        \
    }                                                                        \
    mfma_region<0, 1>(acc, af, bf0, bf1);                                    \
    asm volatile("s_waitcnt lgkmcnt(0)");                                    \
    BARRIER_PINNED;                                                          \
    load_a<dd, 1>(sA, aoff, cs0, cs1, af);                                   \
    if ((tt) + 2 < NT) {                                                     \
      STAGE_A(0, (tt) + 2, dd);                                              \
      STAGE_B(1, (tt) + 2, dd);                                              \
    }                                                                        \
    mfma_region<2, 3>(acc, af, bf0, bf1);                                    \
    if ((tt) + 2 < NT)                                                       \
      asm volatile("s_waitcnt vmcnt(4) lgkmcnt(0)");                         \
    else if ((tt) + 1 < NT)                                                  \
      asm volatile("s_waitcnt vmcnt(0) lgkmcnt(0)");                         \
    else                                                                     \
      asm volatile("s_waitcnt lgkmcnt(0)");                                  \
    BARRIER_PINNED;                                                          \
  } while (0)

// shared K-loop body macro (identical for single and multi variants)
#define GEMM_PREAMBLE_AND_LOOP                                               \
  const int qm = (wid >> 2) * 64;                                            \
  const int qn = (wid & 3) * 32;                                             \
  const int lr = lane & 15;                                                  \
  const int lq = lane >> 4;                                                  \
  const int xr = lane & 7;                                                   \
  const int cs0 = (lq ^ xr) * 8;                                             \
  const int cs1 = ((4 + lq) ^ xr) * 8;                                       \
  const int aoff = (qm + lr) * 64;                                           \
  const int boff = (qn + lr) * 64;                                           \
  const int rl = tid >> 3;                                                   \
  const int j8 = tid & 7;                                                    \
  const int co = (j8 ^ (rl & 7)) * 8;                                        \
  const int lo = tid * 8;                                                    \
  const ushort_t* gA = A + (size_t)(m0 + rl) * K + co;                       \
  const ushort_t* gB = W + (size_t)(n0 + rl) * K + co;                       \
  floatx4 acc[4][4][2] = {};                                                 \
  short8 af[4][2], bf0[2][2], bf1[2][2];                                     \
  STAGE_A(0, 0, 0);                                                          \
  STAGE_B(1, 0, 0);                                                          \
  STAGE_B(0, 0, 0);                                                          \
  STAGE_A(1, 0, 0);                                                          \
  STAGE_A(0, 1, 1);                                                          \
  STAGE_B(1, 1, 1);                                                          \
  asm volatile("s_waitcnt vmcnt(4)");                                        \
  BARRIER_PINNED;                                                            \
  _Pragma("unroll 1")                                                        \
  for (int t = 0; t < NT; t += 2) {                                          \
    GROUP(t, 0);                                                             \
    GROUP(t + 1, 1);                                                         \
  }

// ---------------------------------------------------------------------------
// Single-output GEMM: C[t,n] = sum_k A[t,k]*W[n,k] + bias[n].
// M=16384, N=K=1024. 256x256 tile, 8 waves, 2x4 per-quadrant wave split.
// ---------------------------------------------------------------------------
template <bool RELU, bool OUT32>
__global__ __launch_bounds__(512, 2) void gemm_bt(
    const ushort_t* __restrict__ A, const ushort_t* __restrict__ W,
    const float* __restrict__ bias, void* __restrict__ Cp) {
  constexpr int K = 1024, N = 1024, NT = 16;
  extern __shared__ ushort_t smem[];
  ushort_t* sA = smem;
  ushort_t* sB = smem + 32768;

  const int tid = threadIdx.x;
  const int lane = tid & 63;
  const int wid = tid >> 6;

  // XCD-bijective swizzle: 256 wgs -> 32/XCD; m-panel's 4 n-tiles grouped.
  const int orig = blockIdx.x;
  const int swz = (orig & 7) * 32 + (orig >> 3);
  const int m0 = (swz >> 2) * 256;
  const int n0 = (swz & 3) * 256;

  GEMM_PREAMBLE_AND_LOOP;

  // ---- epilogue. C/D layout: col=lane&15, row=(lane>>4)*4+reg [m89] ----
  const int rbase = lq * 4;

  if constexpr (OUT32) {
    float* sCf = (float*)smem;
#pragma unroll
    for (int p = 0; p < 4; p++) {
      if ((qm >> 6) == (p & 1)) {
#pragma unroll
        for (int Nh = 0; Nh < 2; Nh++)
#pragma unroll
          for (int j = 0; j < 2; j++) {
            const int col = Nh * 128 + qn + j * 16 + lr;
            const float bv = bias[n0 + col];
#pragma unroll
            for (int i = 0; i < 4; i++)
#pragma unroll
              for (int r = 0; r < 4; r++) {
                float v = acc[(p >> 1) * 2 + Nh][i][j][r] + bv;
                if (RELU) v = fmaxf(v, 0.0f);
                sCf[(i * 16 + rbase + r) * 260 + col] = v;
              }
          }
      }
      __syncthreads();
#pragma unroll
      for (int u = 0; u < 8; u++) {
        const int lin = u * 512 + tid;
        const int row = lin >> 6;
        const int c4 = (lin & 63) * 4;
        *(float4*)((float*)Cp + (size_t)(m0 + p * 64 + row) * N + n0 + c4) =
            *(const float4*)&sCf[row * 260 + c4];
      }
      __syncthreads();
    }
    return;
  }

  ushort_t* sC = smem;
#pragma unroll
  for (int p = 0; p < 2; p++) {
#pragma unroll
    for (int Nh = 0; Nh < 2; Nh++)
#pragma unroll
      for (int j = 0; j < 2; j++) {
        const int col = Nh * 128 + qn + j * 16 + lr;
        const float bv = bias[n0 + col];
#pragma unroll
        for (int i = 0; i < 4; i++)
#pragma unroll
          for (int r = 0; r < 4; r++) {
            float v = acc[p * 2 + Nh][i][j][r] + bv;
            if (RELU) v = fmaxf(v, 0.0f);
            sC[(qm + i * 16 + rbase + r) * 264 + col] = f2b(v);
          }
      }
    __syncthreads();
#pragma unroll
    for (int u = 0; u < 8; u++) {
      const int lin = u * 512 + tid;
      const int row = lin >> 5;
      const int c8 = (lin & 31) * 8;
      *(uint4*)((ushort_t*)Cp + (size_t)(m0 + p * 128 + row) * N + n0 + c8) =
          *(const uint4*)&sC[row * 264 + c8];
    }
    __syncthreads();
  }
}

// ---------------------------------------------------------------------------
// Multi-output GEMM: NMAT consecutive 1024x1024 weight matrices treated as
// one (NMAT*1024)-row W; per-1024-col range selects A/bias/output pointers.
// Inner loop byte-identical to gemm_bt. bf16 out only, no relu.
// ---------------------------------------------------------------------------
struct Multi3 {
  const ushort_t* Asrc[3];
  const float* bias[3];
  ushort_t* out[3];
};

template <int NMAT>
__global__ __launch_bounds__(512, 2) void gemm_bt_multi(
    const ushort_t* __restrict__ W, Multi3 mo) {
  constexpr int K = 1024, N = 1024, NT = 16;
  constexpr int NB = NMAT * 4;          // 256-col tiles across fused N
  constexpr int CPX = (64 * NB) / 8;    // wgs per XCD (nwg % 8 == 0)
  extern __shared__ ushort_t smem[];
  ushort_t* sA = smem;
  ushort_t* sB = smem + 32768;

  const int tid = threadIdx.x;
  const int lane = tid & 63;
  const int wid = tid >> 6;

  const int orig = blockIdx.x;
  const int swz = (orig & 7) * CPX + (orig >> 3);
  const int m0 = (swz / NB) * 256;
  const int nn = swz % NB;              // m-panel's NB n-tiles contiguous
  const int n0 = nn * 256;              // row into concatenated W
  const int which = nn >> 2;
  const int nloc = (nn & 3) * 256;      // col offset within the output matrix
  const ushort_t* A = mo.Asrc[which];

  GEMM_PREAMBLE_AND_LOOP;

  const int rbase = lq * 4;
  const float* bias = mo.bias[which];
  ushort_t* Cb = mo.out[which];

  ushort_t* sC = smem;
#pragma unroll
  for (int p = 0; p < 2; p++) {
#pragma unroll
    for (int Nh = 0; Nh < 2; Nh++)
#pragma unroll
      for (int j = 0; j < 2; j++) {
        const int col = Nh * 128 + qn + j * 16 + lr;
        const float bv = bias[nloc + col];
#pragma unroll
        for (int i = 0; i < 4; i++)
#pragma unroll
          for (int r = 0; r < 4; r++) {
            float v = acc[p * 2 + Nh][i][j][r] + bv;
            sC[(qm + i * 16 + rbase + r) * 264 + col] = f2b(v);
          }
      }
    __syncthreads();
#pragma unroll
    for (int u = 0; u < 8; u++) {
      const int lin = u * 512 + tid;
      const int row = lin >> 5;
      const int c8 = (lin & 31) * 8;
      *(uint4*)(Cb + (size_t)(m0 + p * 128 + row) * N + nloc + c8) =
          *(const uint4*)&sC[row * 264 + c8];
    }
    __syncthreads();
  }
}

// ---------------------------------------------------------------------------
// Per-token head-mix attention (bf16). One wave/token, 4 tokens/block.
// O may alias Q: all reads staged to LDS before any global write.
// ---------------------------------------------------------------------------
__global__ __launch_bounds__(256) void attn_kernel(
    const ushort_t* Q, const ushort_t* Kp, const ushort_t* Vp, ushort_t* O) {
  __shared__ __align__(16) ushort_t sq[4][1024];
  __shared__ __align__(16) ushort_t sk[4][1024];
  __shared__ __align__(16) ushort_t sv[4][1024];
  __shared__ float sp[4][64];

  const int t = threadIdx.x;
  const int w = t >> 6;
  const int lane = t & 63;
  const size_t base = ((size_t)blockIdx.x * 4 + w) * 1024;

  ((uint4*)sq[w])[lane] = ((const uint4*)(Q + base))[lane];
  ((uint4*)sq[w])[lane + 64] = ((const uint4*)(Q + base))[lane + 64];
  ((uint4*)sk[w])[lane] = ((const uint4*)(Kp + base))[lane];
  ((uint4*)sk[w])[lane + 64] = ((const uint4*)(Kp + base))[lane + 64];
  ((uint4*)sv[w])[lane] = ((const uint4*)(Vp + base))[lane];
  ((uint4*)sv[w])[lane + 64] = ((const uint4*)(Vp + base))[lane + 64];
  __syncthreads();

  {  // scores + softmax: lane = i*8 + j
    const int i = lane >> 3, j = lane & 7;
    const ushort_t* qr = &sq[w][i * 128];
    const ushort_t* kr = &sk[w][j * 128];
    float s = 0.0f;
#pragma unroll 16
    for (int h = 0; h < 128; h++) s += b2f(qr[h]) * b2f(kr[h]);
    s *= 0.08838834764831845f;  // 1/sqrt(128)
    float m = s;
#pragma unroll
    for (int off = 1; off < 8; off <<= 1) m = fmaxf(m, __shfl_xor(m, off, 64));
    float e = __expf(s - m);
    float sum = e;
#pragma unroll
    for (int off = 1; off < 8; off <<= 1) sum += __shfl_xor(sum, off, 64);
    sp[w][lane] = e / sum;
  }
  __syncthreads();

  {  // out[i][h] = sum_j P[i][j]*v[j][h]
    const int i = lane >> 3;
    const int hb = (lane & 7) * 16;
    float p[8];
#pragma unroll
    for (int jj = 0; jj < 8; jj++) p[jj] = sp[w][i * 8 + jj];
    float o[16];
#pragma unroll
    for (int h = 0; h < 16; h++) {
      float acc = 0.0f;
#pragma unroll
      for (int jj = 0; jj < 8; jj++) acc += p[jj] * b2f(sv[w][jj * 128 + hb + h]);
      o[h] = acc;
    }
    uint32_t packed[8];
#pragma unroll
    for (int u = 0; u < 8; u++)
      packed[u] = (uint32_t)f2b(o[2 * u]) | ((uint32_t)f2b(o[2 * u + 1]) << 16);
    uint4* dst = (uint4*)(O + base + i * 128 + hb);
    dst[0] = *(uint4*)&packed[0];
    dst[1] = *(uint4*)&packed[4];
  }
}

// ---------------------------------------------------------------------------
extern "C" void kernel_launch(void* const* d_in, const int* in_sizes, int n_in,
                              void* d_out, int out_size, void* d_ws, size_t ws_size,
                              hipStream_t stream) {
  const float* input_seq = (const float*)d_in[0];
  const float* output_seq = (const float*)d_in[1];
  const float* pe = (const float*)d_in[2];
  const float* wsrc[14] = {
      (const float*)d_in[3],  (const float*)d_in[5],  (const float*)d_in[7],
      (const float*)d_in[9],  (const float*)d_in[11], (const float*)d_in[13],
      (const float*)d_in[15], (const float*)d_in[17], (const float*)d_in[19],
      (const float*)d_in[21], (const float*)d_in[23], (const float*)d_in[25],
      (const float*)d_in[27], (const float*)d_in[29]};
  const float* enc_bq = (const float*)d_in[4];
  const float* enc_bk = (const float*)d_in[6];
  const float* enc_bv = (const float*)d_in[8];
  const float* enc_b1 = (const float*)d_in[10];
  const float* enc_b2 = (const float*)d_in[12];
  const float* dsq_b = (const float*)d_in[14];
  const float* dsk_b = (const float*)d_in[16];
  const float* dsv_b = (const float*)d_in[18];
  const float* dcq_b = (const float*)d_in[20];
  const float* dck_b = (const float*)d_in[22];
  const float* dcv_b = (const float*)d_in[24];
  const float* dec_b1 = (const float*)d_in[26];
  const float* dec_b2 = (const float*)d_in[28];
  const float* fc_b = (const float*)d_in[30];

  const size_t SZ = (size_t)TOKENS * DMODEL;   // 16.7M elems
  const size_t WSZ = (size_t)DMODEL * DMODEL;  // 1M elems
  ushort_t* bA = (ushort_t*)d_ws;        // 32MB
  ushort_t* bB = bA + SZ;                // 32MB
  ushort_t* oseq = bB + SZ;              // 32MB (output_seq bf16; later v3)
  ushort_t* wts = oseq + SZ;             // 28MB bf16 weights
  ushort_t* oL = (ushort_t*)d_out;       // d_out lower 32MB as bf16 scratch
  ushort_t* oH = oL + SZ;                // d_out upper 32MB as bf16 scratch
  float* outf = (float*)d_out;

  // opt in to 128 KiB dynamic LDS (once per process)
  static bool attr_set = false;
  if (!attr_set) {
    (void)hipFuncSetAttribute(reinterpret_cast<const void*>(&gemm_bt<false, false>),
                              hipFuncAttributeMaxDynamicSharedMemorySize, 131072);
    (void)hipFuncSetAttribute(reinterpret_cast<const void*>(&gemm_bt<true, false>),
                              hipFuncAttributeMaxDynamicSharedMemorySize, 131072);
    (void)hipFuncSetAttribute(reinterpret_cast<const void*>(&gemm_bt<false, true>),
                              hipFuncAttributeMaxDynamicSharedMemorySize, 131072);
    (void)hipFuncSetAttribute(reinterpret_cast<const void*>(&gemm_bt_multi<3>),
                              hipFuncAttributeMaxDynamicSharedMemorySize, 131072);
    attr_set = true;
  }

  // weight idx: 0 ewq,1 ewk,2 ewv,3 ew1,4 ew2,5 dsq,6 dsk,7 dsv,8 dcq,9 dck,
  //             10 dcv,11 dw1,12 dw2,13 fc
  PreArgs pa;
#pragma unroll
  for (int i = 0; i < 14; i++) pa.wsrc[i] = wsrc[i];
  pa.wdst = wts;
  pa.oseq_src = output_seq; pa.oseq_dst = oseq;
  pa.in_seq = input_seq; pa.pe = pe; pa.x_dst = bA;

  const dim3 gG(TOKENS / 256 * (DMODEL / 256));  // 256 wgs
  const dim3 gG3(TOKENS / 256 * 12);             // 768 wgs (NMAT=3)
  const dim3 gblk(512);
  const dim3 blk(256);
  const int LDSB = 131072;
  const int gPRE = 14 * 512 + 8192 + 8192;       // 23552
  const int gAT = TOKENS / 4;                    // 4096

  // 1. merged preprocessing: weights->bf16, oseq->bf16, bA = x = in+pe
  preproc_kernel<<<gPRE, blk, 0, stream>>>(pa);

  // 2. encoder self-attn: fused QKV (W 0..2)
  Multi3 eqkv = {{bA, bA, bA}, {enc_bq, enc_bk, enc_bv}, {bB, oL, oH}};
  gemm_bt_multi<3><<<gG3, gblk, LDSB, stream>>>(wts + 0 * WSZ, eqkv);
  attn_kernel<<<gAT, blk, 0, stream>>>(bB, oL, oH, bB);                        // bB = a
  // 3. encoder FFN
  gemm_bt<true, false><<<gG, gblk, LDSB, stream>>>(bB, wts + 3 * WSZ, enc_b1, bA);   // bA = h1
  gemm_bt<false, false><<<gG, gblk, LDSB, stream>>>(bA, wts + 4 * WSZ, enc_b2, bB);  // bB = enc_out
  // 4. decoder self-attn: fused QKV (W 5..7)
  Multi3 dqkv = {{oseq, oseq, oseq}, {dsq_b, dsk_b, dsv_b}, {bA, oL, oH}};
  gemm_bt_multi<3><<<gG3, gblk, LDSB, stream>>>(wts + 5 * WSZ, dqkv);
  attn_kernel<<<gAT, blk, 0, stream>>>(bA, oL, oH, bA);                        // bA = sa
  // 5. decoder cross-attn: fused q3(A=sa) + k3/v3(A=enc_out); W 8..10
  //    v3 -> oseq (dead after decQKV) to avoid writing a buffer read here.
  Multi3 dq3kv = {{bA, bB, bB}, {dcq_b, dck_b, dcv_b}, {oL, oH, oseq}};
  gemm_bt_multi<3><<<gG3, gblk, LDSB, stream>>>(wts + 8 * WSZ, dq3kv);
  attn_kernel<<<gAT, blk, 0, stream>>>(oL, oH, oseq, oL);                      // oL = ca
  // 6. decoder FFN + final fc
  gemm_bt<true, false><<<gG, gblk, LDSB, stream>>>(oL, wts + 11 * WSZ, dec_b1, bB);  // bB = h2
  gemm_bt<false, false><<<gG, gblk, LDSB, stream>>>(bB, wts + 12 * WSZ, dec_b2, bA); // bA = dec_out
  gemm_bt<false, true><<<gG, gblk, LDSB, stream>>>(bA, wts + 13 * WSZ, fc_b, outf);  // d_out fp32
}